// Round 6
// baseline (510.727 us; speedup 1.0000x reference)
//
#include <hip/hip_runtime.h>

#define SEQ    2048
#define DM     2048
#define QKVN   3072
#define VTR    64

typedef short s16x8 __attribute__((ext_vector_type(8)));
typedef float f32x4 __attribute__((ext_vector_type(4)));
typedef unsigned short us;

#define MFMA(a,b,c) __builtin_amdgcn_mfma_f32_16x16x32_bf16((a),(b),(c),0,0,0)

__device__ __forceinline__ float bf2f(us u) {
    unsigned v = ((unsigned)u) << 16;
    return __builtin_bit_cast(float, v);
}
__device__ __forceinline__ us f2bf(float f) {
    unsigned u = __builtin_bit_cast(unsigned, f);
    u += 0x7FFFu + ((u >> 16) & 1u);
    return (us)(u >> 16);
}
// pack 4 f32 -> 4 truncated bf16, single b64 LDS store
__device__ __forceinline__ void packstore4(us* p, float a, float b, float c, float d) {
    unsigned d0 = (__builtin_bit_cast(unsigned, a) >> 16) |
                  (__builtin_bit_cast(unsigned, b) & 0xFFFF0000u);
    unsigned d1 = (__builtin_bit_cast(unsigned, c) >> 16) |
                  (__builtin_bit_cast(unsigned, d) & 0xFFFF0000u);
    *(uint2*)p = make_uint2(d0, d1);
}
__device__ __forceinline__ void glds16(const us* g, us* l) {
    __builtin_amdgcn_global_load_lds((__attribute__((address_space(1))) void*)g,
                                     (__attribute__((address_space(3))) void*)l, 16, 0, 0);
}

// ---------------------------------------------------------------------------
__global__ __launch_bounds__(256) void cvt_f32_bf16(const float* __restrict__ src,
                                                    us* __restrict__ dst, int n4) {
    int i = blockIdx.x * blockDim.x + threadIdx.x;
    if (i >= n4) return;
    float4 v = ((const float4*)src)[i];
    ushort4 o;
    o.x = f2bf(v.x); o.y = f2bf(v.y); o.z = f2bf(v.z); o.w = f2bf(v.w);
    ((ushort4*)dst)[i] = o;
}

// all 4 weight tensors -> one contiguous bf16 region (wq|wk|wv|wo)
__global__ __launch_bounds__(256) void cvt_weights(const float* __restrict__ wq,
                                                   const float* __restrict__ wk,
                                                   const float* __restrict__ wv,
                                                   const float* __restrict__ wo,
                                                   us* __restrict__ dst) {
    int i = blockIdx.x * blockDim.x + threadIdx.x;   // float4 index, total 2621440
    const float* src;
    int off;
    if (i < 1048576)      { src = wq; off = 0; }
    else if (i < 1310720) { src = wk; off = 1048576; }
    else if (i < 1572864) { src = wv; off = 1310720; }
    else                  { src = wo; off = 1572864; }
    float4 v = ((const float4*)src)[i - off];
    ushort4 o;
    o.x = f2bf(v.x); o.y = f2bf(v.y); o.z = f2bf(v.z); o.w = f2bf(v.w);
    ((ushort4*)dst)[i] = o;
}

// ---------------------------------------------------------------------------
// GEMM m97-structure, 128x128 tile, BK=32, global_load_lds width-16 staging.
// ROPE=true: rotary on cols<2560 of the fused QKV output.
// ---------------------------------------------------------------------------
template <typename OutT, bool ROPE>
__global__ __launch_bounds__(256) void gemm_bt(const us* __restrict__ A, const us* __restrict__ W,
                                               OutT* __restrict__ C, int M, int N, int K) {
    __shared__ us la[128 * 32];
    __shared__ us lb[128 * 32];
    const int tid = threadIdx.x, lane = tid & 63, wave = tid >> 6;
    const int quad = lane >> 4, lr = lane & 15;
    const int m0 = blockIdx.x * 128, n0 = blockIdx.y * 128;
    const int wm = (wave & 1) * 64, wn = (wave >> 1) * 64;

    f32x4 acc[4][4] = {};

    const int r0 = wave * 32 + (lane >> 2);
    const int c0 = (lane & 3) * 8;
    const us* ga0 = A + (size_t)(m0 + r0) * K + c0;
    const us* ga1 = A + (size_t)(m0 + r0 + 16) * K + c0;
    const us* gb0 = W + (size_t)(n0 + r0) * K + c0;
    const us* gb1 = W + (size_t)(n0 + r0 + 16) * K + c0;
    us* lpa0 = &la[(wave * 32) * 32];
    us* lpa1 = &la[(wave * 32 + 16) * 32];
    us* lpb0 = &lb[(wave * 32) * 32];
    us* lpb1 = &lb[(wave * 32 + 16) * 32];

    for (int k0 = 0; k0 < K; k0 += 32) {
        glds16(ga0 + k0, lpa0);
        glds16(ga1 + k0, lpa1);
        glds16(gb0 + k0, lpb0);
        glds16(gb1 + k0, lpb1);
        __syncthreads();
        s16x8 af[4], bf[4];
#pragma unroll
        for (int i = 0; i < 4; i++) af[i] = *(const s16x8*)&la[(wm + i * 16 + lr) * 32 + quad * 8];
#pragma unroll
        for (int j = 0; j < 4; j++) bf[j] = *(const s16x8*)&lb[(wn + j * 16 + lr) * 32 + quad * 8];
#pragma unroll
        for (int i = 0; i < 4; i++)
#pragma unroll
            for (int j = 0; j < 4; j++)
                acc[i][j] = MFMA(af[i], bf[j], acc[i][j]);
        __syncthreads();
    }

#pragma unroll
    for (int i = 0; i < 4; i++)
#pragma unroll
        for (int j = 0; j < 4; j++)
#pragma unroll
            for (int r = 0; r < 4; r++) {
                int row = m0 + wm + i * 16 + quad * 4 + r;
                int col = n0 + wn + j * 16 + lr;
                float v = acc[i][j][r];
                if (ROPE && n0 < 2560) {
                    int pair = (col >> 1) & 31;
                    float inv = exp2f((float)pair * (-13.2877124f / 32.0f));
                    float ang = (float)(row & (SEQ - 1)) * inv;
                    float c = __cosf(ang), sn = __sinf(ang);
                    float p = __shfl_xor(v, 1);
                    v = v * c + ((col & 1) ? p * sn : -p * sn);
                }
                if constexpr (sizeof(OutT) == 2)
                    C[(size_t)row * N + col] = f2bf(v);
                else
                    C[(size_t)row * N + col] = v;
            }
}

// ---------------------------------------------------------------------------
// V transpose from fused qkv buffer (V at col 2560) -> vt (b,kvh, 64, S)
// ---------------------------------------------------------------------------
__global__ __launch_bounds__(256) void transpose_v(const us* __restrict__ qkv, us* __restrict__ vt) {
    __shared__ us tile[64][72];
    const int s0 = blockIdx.x * 64;
    const int bk = blockIdx.y;
    const int b = bk >> 3, kvh = bk & 7;
    const int t = threadIdx.x;
    const int r = t >> 3, cg = (t & 7) * 8;
#pragma unroll
    for (int p = 0; p < 2; p++) {
        int rr = r + p * 32;
        *(s16x8*)&tile[rr][cg] =
            *(const s16x8*)(qkv + (size_t)(b * SEQ + s0 + rr) * QKVN + 2560 + kvh * 64 + cg);
    }
    __syncthreads();
#pragma unroll
    for (int p = 0; p < 2; p++) {
        int d = r + p * 32;
        s16x8 val;
#pragma unroll
        for (int u = 0; u < 8; u++) val[u] = tile[cg + u][d];
        *(s16x8*)(vt + ((size_t)bk * VTR + d) * SEQ + s0 + cg) = val;
    }
}

// ---------------------------------------------------------------------------
// Causal flash attention. Each wave owns TWO 16-row q-tiles (qtL, qtH=31-qtL)
// sharing one K-loop. QK^T computed TRANSPOSED (MFMA(kf,qa) -> S^T in C-layout:
// col=q, row=key) so each lane holds 4 consecutive keys of one q-row -> P
// written to LDS with one b64 store per 16-key chunk (LDS-pipe pressure was
// the R5 bottleneck: 36 -> 12 DS ops/iter). PV side unchanged (P read as
// A-frag, V^T as B-frag). No softmax reductions; l via ones-column MFMA.
// ---------------------------------------------------------------------------
__global__ __launch_bounds__(256, 3) void flash_attn(const us* __restrict__ qkv,
                                                     const us* __restrict__ vt,
                                                     us* __restrict__ o) {
    __shared__ us P[4][2][16 * 72];
    const int bh = blockIdx.y, b = bh >> 5, h = bh & 31, kvh = h >> 2;
    const int wave = threadIdx.x >> 6, lane = threadIdx.x & 63;
    const int quad = lane >> 4, lr = lane & 15;
    const int pairi = (blockIdx.x + (blockIdx.y >> 2)) & 15;
    const int qtL = pairi, qtH = 31 - pairi;
    const int q0L = qtL * 64 + wave * 16, q0H = qtH * 64 + wave * 16;
    const us* kbase = qkv + (size_t)b * SEQ * QKVN + 2048 + kvh * 64;
    const us* vb = vt + (size_t)(b * 8 + kvh) * VTR * SEQ;
    us* PL = &P[wave][0][0];
    us* PH = &P[wave][1][0];
    const float QS = 0.125f * 1.44269504f;   // scale * log2(e)

    s16x8 onesb;
    const short ov = (lr == 0) ? (short)0x3F80 : (short)0;
#pragma unroll
    for (int j = 0; j < 8; j++) onesb[j] = ov;

    const us* qbL = qkv + (size_t)(b * SEQ + q0L) * QKVN + h * 64;
    const us* qbH = qkv + (size_t)(b * SEQ + q0H) * QKVN + h * 64;
    s16x8 qaL0 = *(const s16x8*)(qbL + (size_t)lr * QKVN + quad * 8);
    s16x8 qaL1 = *(const s16x8*)(qbL + (size_t)lr * QKVN + 32 + quad * 8);
    s16x8 qaH0 = *(const s16x8*)(qbH + (size_t)lr * QKVN + quad * 8);
    s16x8 qaH1 = *(const s16x8*)(qbH + (size_t)lr * QKVN + 32 + quad * 8);
#pragma unroll
    for (int j = 0; j < 8; j++) {
        qaL0[j] = (short)f2bf(bf2f((us)qaL0[j]) * QS);
        qaL1[j] = (short)f2bf(bf2f((us)qaL1[j]) * QS);
        qaH0[j] = (short)f2bf(bf2f((us)qaH0[j]) * QS);
        qaH1[j] = (short)f2bf(bf2f((us)qaH1[j]) * QS);
    }

    f32x4 oL[5] = {}, oH[5] = {};
    s16x8 kf[8];
    {
        const us* kp = kbase + (size_t)lr * QKVN;
#pragma unroll
        for (int nb = 0; nb < 4; nb++) {
            kf[2 * nb]     = *(const s16x8*)(kp + (size_t)nb * 16 * QKVN + quad * 8);
            kf[2 * nb + 1] = *(const s16x8*)(kp + (size_t)nb * 16 * QKVN + 32 + quad * 8);
        }
    }

    for (int kb = 0; kb <= qtH; kb++) {
        const bool aL = (kb <= qtL);
        // S^T = K Q^T : A=kf (m=key), B=qa (n=q). C: col=lr=q, row=quad*4+r=key.
        f32x4 scH[4] = {}, scL[4] = {};
#pragma unroll
        for (int nb = 0; nb < 4; nb++) {
            scH[nb] = MFMA(kf[2 * nb], qaH0, scH[nb]);
            scH[nb] = MFMA(kf[2 * nb + 1], qaH1, scH[nb]);
        }
        if (aL) {
#pragma unroll
            for (int nb = 0; nb < 4; nb++) {
                scL[nb] = MFMA(kf[2 * nb], qaL0, scL[nb]);
                scL[nb] = MFMA(kf[2 * nb + 1], qaL1, scL[nb]);
            }
        }
        // V loads before kf prefetch: PV's vmcnt wait won't drain next K tile.
        s16x8 vf[8];
#pragma unroll
        for (int n = 0; n < 4; n++)
#pragma unroll
            for (int kc = 0; kc < 2; kc++)
                vf[n * 2 + kc] = *(const s16x8*)(vb + (size_t)(n * 16 + lr) * SEQ +
                                                 kb * 64 + kc * 32 + quad * 8);
        if (kb < qtH) {
            const us* kp = kbase + (size_t)((kb + 1) * 64 + lr) * QKVN;
#pragma unroll
            for (int nb = 0; nb < 4; nb++) {
                kf[2 * nb]     = *(const s16x8*)(kp + (size_t)nb * 16 * QKVN + quad * 8);
                kf[2 * nb + 1] = *(const s16x8*)(kp + (size_t)nb * 16 * QKVN + 32 + quad * 8);
            }
        }
        // P rows: lane holds keys {kb*64+nb*16+quad*4+r}, q = q0+lr -> b64 packs
        const int kloc = kb * 64 + quad * 4;
        if (kb == qtH) {
            const int q = q0H + lr;
#pragma unroll
            for (int nb = 0; nb < 4; nb++) {
                int k0 = kloc + nb * 16;
                float e0 = (k0     > q) ? 0.f : exp2f(scH[nb][0]);
                float e1 = (k0 + 1 > q) ? 0.f : exp2f(scH[nb][1]);
                float e2 = (k0 + 2 > q) ? 0.f : exp2f(scH[nb][2]);
                float e3 = (k0 + 3 > q) ? 0.f : exp2f(scH[nb][3]);
                packstore4(&PH[lr * 72 + nb * 16 + quad * 4], e0, e1, e2, e3);
            }
        } else {
#pragma unroll
            for (int nb = 0; nb < 4; nb++)
                packstore4(&PH[lr * 72 + nb * 16 + quad * 4],
                           exp2f(scH[nb][0]), exp2f(scH[nb][1]),
                           exp2f(scH[nb][2]), exp2f(scH[nb][3]));
        }
        if (aL) {
            if (kb == qtL) {
                const int q = q0L + lr;
#pragma unroll
                for (int nb = 0; nb < 4; nb++) {
                    int k0 = kloc + nb * 16;
                    float e0 = (k0     > q) ? 0.f : exp2f(scL[nb][0]);
                    float e1 = (k0 + 1 > q) ? 0.f : exp2f(scL[nb][1]);
                    float e2 = (k0 + 2 > q) ? 0.f : exp2f(scL[nb][2]);
                    float e3 = (k0 + 3 > q) ? 0.f : exp2f(scL[nb][3]);
                    packstore4(&PL[lr * 72 + nb * 16 + quad * 4], e0, e1, e2, e3);
                }
            } else {
#pragma unroll
                for (int nb = 0; nb < 4; nb++)
                    packstore4(&PL[lr * 72 + nb * 16 + quad * 4],
                               exp2f(scL[nb][0]), exp2f(scL[nb][1]),
                               exp2f(scL[nb][2]), exp2f(scL[nb][3]));
            }
        }
        // per-wave DS ops execute in order: compiler barrier only, no hw wait
        asm volatile("" ::: "memory");
#pragma unroll
        for (int kc = 0; kc < 2; kc++) {
            s16x8 paH = *(const s16x8*)&PH[lr * 72 + kc * 32 + quad * 8];
#pragma unroll
            for (int n = 0; n < 4; n++)
                oH[n] = MFMA(paH, vf[n * 2 + kc], oH[n]);
            oH[4] = MFMA(paH, onesb, oH[4]);
        }
        if (aL) {
#pragma unroll
            for (int kc = 0; kc < 2; kc++) {
                s16x8 paL = *(const s16x8*)&PL[lr * 72 + kc * 32 + quad * 8];
#pragma unroll
                for (int n = 0; n < 4; n++)
                    oL[n] = MFMA(paL, vf[n * 2 + kc], oL[n]);
                oL[4] = MFMA(paL, onesb, oL[4]);
            }
        }
    }

#pragma unroll
    for (int r = 0; r < 4; r++) {
        float lH = __shfl(oH[4][r], lane & 48);
        float liH = 1.0f / lH;
        float lL = __shfl(oL[4][r], lane & 48);
        float liL = 1.0f / lL;
#pragma unroll
        for (int n = 0; n < 4; n++) {
            o[(size_t)(b * SEQ + q0H + quad * 4 + r) * DM + h * 64 + n * 16 + lr] =
                f2bf(oH[n][r] * liH);
            o[(size_t)(b * SEQ + q0L + quad * 4 + r) * DM + h * 64 + n * 16 + lr] =
                f2bf(oL[n][r] * liL);
        }
    }
}

// ---------------------------------------------------------------------------
extern "C" void kernel_launch(void* const* d_in, const int* in_sizes, int n_in,
                              void* d_out, int out_size, void* d_ws, size_t ws_size,
                              hipStream_t stream) {
    const float* x  = (const float*)d_in[0];
    const float* wq = (const float*)d_in[1];
    const float* wk = (const float*)d_in[2];
    const float* wv = (const float*)d_in[3];
    const float* wo = (const float*)d_in[4];
    float* out = (float*)d_out;

    char* ws = (char*)d_ws;
    const size_t MB = 1024 * 1024;
    us* xb     = (us*)(ws + 0 * MB);    // 16 MiB; reused as abuf (flash out)
    us* abuf   = (us*)(ws + 0 * MB);
    us* wqkvb  = (us*)(ws + 16 * MB);   // 12 MiB (wq|wk|wv) — contiguous with wob
    us* wob    = (us*)(ws + 28 * MB);   // 8 MiB
    us* qkvbuf = (us*)(ws + 36 * MB);   // 24 MiB (4096 x 3072)
    us* vtbuf  = (us*)(ws + 60 * MB);   // 4 MiB

    dim3 blk(256);
    cvt_f32_bf16<<<dim3(8192), blk, 0, stream>>>(x, xb, 2097152);
    cvt_weights<<<dim3(10240), blk, 0, stream>>>(wq, wk, wv, wo, wqkvb);

    gemm_bt<us, true><<<dim3(32, 24), blk, 0, stream>>>(xb, wqkvb, qkvbuf, 4096, 3072, 2048);
    transpose_v<<<dim3(32, 16), blk, 0, stream>>>(qkvbuf, vtbuf);
    flash_attn<<<dim3(16, 64), blk, 0, stream>>>(qkvbuf, vtbuf, abuf);
    gemm_bt<float, false><<<dim3(32, 16), blk, 0, stream>>>(abuf, wob, out, 4096, 2048, 2048);
}

// Round 7
// 385.901 us; speedup vs baseline: 1.3235x; 1.3235x over previous
//
#include <hip/hip_runtime.h>

#define SEQ    2048
#define DM     2048
#define QKVN   3072
#define VTR    64

typedef short s16x8 __attribute__((ext_vector_type(8)));
typedef float f32x4 __attribute__((ext_vector_type(4)));
typedef unsigned short us;

#define MFMA(a,b,c) __builtin_amdgcn_mfma_f32_16x16x32_bf16((a),(b),(c),0,0,0)

__device__ __forceinline__ float bf2f(us u) {
    unsigned v = ((unsigned)u) << 16;
    return __builtin_bit_cast(float, v);
}
__device__ __forceinline__ us f2bf(float f) {
    unsigned u = __builtin_bit_cast(unsigned, f);
    u += 0x7FFFu + ((u >> 16) & 1u);
    return (us)(u >> 16);
}
// truncating bf16 store (folds to ds_write_b16_d16_hi) — R5-proven
__device__ __forceinline__ void stp(us* p, float f) {
    *p = (us)(__builtin_bit_cast(unsigned, f) >> 16);
}
__device__ __forceinline__ void glds16(const us* g, us* l) {
    __builtin_amdgcn_global_load_lds((__attribute__((address_space(1))) void*)g,
                                     (__attribute__((address_space(3))) void*)l, 16, 0, 0);
}

// ---------------------------------------------------------------------------
__global__ __launch_bounds__(256) void cvt_f32_bf16(const float* __restrict__ src,
                                                    us* __restrict__ dst, int n4) {
    int i = blockIdx.x * blockDim.x + threadIdx.x;
    if (i >= n4) return;
    float4 v = ((const float4*)src)[i];
    ushort4 o;
    o.x = f2bf(v.x); o.y = f2bf(v.y); o.z = f2bf(v.z); o.w = f2bf(v.w);
    ((ushort4*)dst)[i] = o;
}

// all 4 weight tensors -> one contiguous bf16 region (wq|wk|wv|wo)
__global__ __launch_bounds__(256) void cvt_weights(const float* __restrict__ wq,
                                                   const float* __restrict__ wk,
                                                   const float* __restrict__ wv,
                                                   const float* __restrict__ wo,
                                                   us* __restrict__ dst) {
    int i = blockIdx.x * blockDim.x + threadIdx.x;   // float4 index, total 2621440
    const float* src;
    int off;
    if (i < 1048576)      { src = wq; off = 0; }
    else if (i < 1310720) { src = wk; off = 1048576; }
    else if (i < 1572864) { src = wv; off = 1310720; }
    else                  { src = wo; off = 1572864; }
    float4 v = ((const float4*)src)[i - off];
    ushort4 o;
    o.x = f2bf(v.x); o.y = f2bf(v.y); o.z = f2bf(v.z); o.w = f2bf(v.w);
    ((ushort4*)dst)[i] = o;
}

// ---------------------------------------------------------------------------
// GEMM m97-structure, 128x128 tile, BK=32, global_load_lds width-16 staging.
// ROPE=true: rotary on cols<2560 of the fused QKV output.
// ---------------------------------------------------------------------------
template <typename OutT, bool ROPE>
__global__ __launch_bounds__(256) void gemm_bt(const us* __restrict__ A, const us* __restrict__ W,
                                               OutT* __restrict__ C, int M, int N, int K) {
    __shared__ us la[128 * 32];
    __shared__ us lb[128 * 32];
    const int tid = threadIdx.x, lane = tid & 63, wave = tid >> 6;
    const int quad = lane >> 4, lr = lane & 15;
    const int m0 = blockIdx.x * 128, n0 = blockIdx.y * 128;
    const int wm = (wave & 1) * 64, wn = (wave >> 1) * 64;

    f32x4 acc[4][4] = {};

    const int r0 = wave * 32 + (lane >> 2);
    const int c0 = (lane & 3) * 8;
    const us* ga0 = A + (size_t)(m0 + r0) * K + c0;
    const us* ga1 = A + (size_t)(m0 + r0 + 16) * K + c0;
    const us* gb0 = W + (size_t)(n0 + r0) * K + c0;
    const us* gb1 = W + (size_t)(n0 + r0 + 16) * K + c0;
    us* lpa0 = &la[(wave * 32) * 32];
    us* lpa1 = &la[(wave * 32 + 16) * 32];
    us* lpb0 = &lb[(wave * 32) * 32];
    us* lpb1 = &lb[(wave * 32 + 16) * 32];

    for (int k0 = 0; k0 < K; k0 += 32) {
        glds16(ga0 + k0, lpa0);
        glds16(ga1 + k0, lpa1);
        glds16(gb0 + k0, lpb0);
        glds16(gb1 + k0, lpb1);
        __syncthreads();
        s16x8 af[4], bf[4];
#pragma unroll
        for (int i = 0; i < 4; i++) af[i] = *(const s16x8*)&la[(wm + i * 16 + lr) * 32 + quad * 8];
#pragma unroll
        for (int j = 0; j < 4; j++) bf[j] = *(const s16x8*)&lb[(wn + j * 16 + lr) * 32 + quad * 8];
#pragma unroll
        for (int i = 0; i < 4; i++)
#pragma unroll
            for (int j = 0; j < 4; j++)
                acc[i][j] = MFMA(af[i], bf[j], acc[i][j]);
        __syncthreads();
    }

#pragma unroll
    for (int i = 0; i < 4; i++)
#pragma unroll
        for (int j = 0; j < 4; j++)
#pragma unroll
            for (int r = 0; r < 4; r++) {
                int row = m0 + wm + i * 16 + quad * 4 + r;
                int col = n0 + wn + j * 16 + lr;
                float v = acc[i][j][r];
                if (ROPE && n0 < 2560) {
                    int pair = (col >> 1) & 31;
                    float inv = exp2f((float)pair * (-13.2877124f / 32.0f));
                    float ang = (float)(row & (SEQ - 1)) * inv;
                    float c = __cosf(ang), sn = __sinf(ang);
                    float p = __shfl_xor(v, 1);
                    v = v * c + ((col & 1) ? p * sn : -p * sn);
                }
                if constexpr (sizeof(OutT) == 2)
                    C[(size_t)row * N + col] = f2bf(v);
                else
                    C[(size_t)row * N + col] = v;
            }
}

// ---------------------------------------------------------------------------
// V transpose from fused qkv buffer (V at col 2560) -> vt (b,kvh, 64, S)
// ---------------------------------------------------------------------------
__global__ __launch_bounds__(256) void transpose_v(const us* __restrict__ qkv, us* __restrict__ vt) {
    __shared__ us tile[64][72];
    const int s0 = blockIdx.x * 64;
    const int bk = blockIdx.y;
    const int b = bk >> 3, kvh = bk & 7;
    const int t = threadIdx.x;
    const int r = t >> 3, cg = (t & 7) * 8;
#pragma unroll
    for (int p = 0; p < 2; p++) {
        int rr = r + p * 32;
        *(s16x8*)&tile[rr][cg] =
            *(const s16x8*)(qkv + (size_t)(b * SEQ + s0 + rr) * QKVN + 2560 + kvh * 64 + cg);
    }
    __syncthreads();
#pragma unroll
    for (int p = 0; p < 2; p++) {
        int d = r + p * 32;
        s16x8 val;
#pragma unroll
        for (int u = 0; u < 8; u++) val[u] = tile[cg + u][d];
        *(s16x8*)(vt + ((size_t)bk * VTR + d) * SEQ + s0 + cg) = val;
    }
}

// ---------------------------------------------------------------------------
// Causal flash attention. Each wave owns FOUR 16-row q-tiles
// {p, 15-p, 16+p, 31-p} (uniform 66 MFMA-units/wave) sharing one K-loop:
// one kf/vf load set feeds up to 72 MFMAs. Grid (8, B*H) = 512 blocks ->
// 2 block-generations/CU instead of 4 (R5) at the same 8-waves/CU occupancy.
// P-store scheme = R5-proven scalar stp + lgkmcnt(0) (R6's b64 pack regressed:
// +100MB HBM writes). No softmax reductions; l via ones-column MFMA.
// ---------------------------------------------------------------------------
__global__ __launch_bounds__(256, 2) void flash_attn(const us* __restrict__ qkv,
                                                     const us* __restrict__ vt,
                                                     us* __restrict__ o) {
    __shared__ us P[4][4][16 * 72];           // [wave][tile]
    const int bh = blockIdx.y, b = bh >> 5, h = bh & 31, kvh = h >> 2;
    const int wave = threadIdx.x >> 6, lane = threadIdx.x & 63;
    const int quad = lane >> 4, lr = lane & 15;
    const int p = ((int)blockIdx.x + (int)(blockIdx.y >> 3)) & 7;
    const int qts[4] = {p, 15 - p, 16 + p, 31 - p};
    const us* kbase = qkv + (size_t)b * SEQ * QKVN + 2048 + kvh * 64;
    const us* vb = vt + (size_t)(b * 8 + kvh) * VTR * SEQ;
    const float QS = 0.125f * 1.44269504f;    // scale * log2(e)

    s16x8 onesb;
    const short ov = (lr == 0) ? (short)0x3F80 : (short)0;
#pragma unroll
    for (int j = 0; j < 8; j++) onesb[j] = ov;

    int q0[4];
    s16x8 qa[4][2];
#pragma unroll
    for (int t = 0; t < 4; t++) {
        q0[t] = qts[t] * 64 + wave * 16;
        const us* qb = qkv + (size_t)(b * SEQ + q0[t]) * QKVN + h * 64;
        qa[t][0] = *(const s16x8*)(qb + (size_t)lr * QKVN + quad * 8);
        qa[t][1] = *(const s16x8*)(qb + (size_t)lr * QKVN + 32 + quad * 8);
#pragma unroll
        for (int j = 0; j < 8; j++) {
            qa[t][0][j] = (short)f2bf(bf2f((us)qa[t][0][j]) * QS);
            qa[t][1][j] = (short)f2bf(bf2f((us)qa[t][1][j]) * QS);
        }
    }

    f32x4 oacc[4][5] = {};                    // per tile: [0..3]=O, [4] col0 = l
    s16x8 kf[8];
    {
        const us* kp = kbase + (size_t)lr * QKVN;
#pragma unroll
        for (int nb = 0; nb < 4; nb++) {
            kf[2 * nb]     = *(const s16x8*)(kp + (size_t)nb * 16 * QKVN + quad * 8);
            kf[2 * nb + 1] = *(const s16x8*)(kp + (size_t)nb * 16 * QKVN + 32 + quad * 8);
        }
    }

    // QK for one tile -> sc; exp2 -> P[wave][t] (scalar b16 stores, R5-proven)
    auto qk_tile = [&](int t, f32x4* sc) {
#pragma unroll
        for (int nb = 0; nb < 4; nb++) {
            sc[nb] = f32x4{0.f, 0.f, 0.f, 0.f};
            sc[nb] = MFMA(qa[t][0], kf[2 * nb], sc[nb]);
            sc[nb] = MFMA(qa[t][1], kf[2 * nb + 1], sc[nb]);
        }
    };
    auto store_tile = [&](int t, const f32x4* sc, int kb) {
        us* Pt = &P[wave][t][0];
        if (kb == qts[t]) {                   // diagonal block: causal mask
#pragma unroll
            for (int nb = 0; nb < 4; nb++)
#pragma unroll
                for (int r = 0; r < 4; r++) {
                    int key = kb * 64 + nb * 16 + lr, row = q0[t] + quad * 4 + r;
                    float s = (key > row) ? -1e30f : sc[nb][r];
                    stp(&Pt[(quad * 4 + r) * 72 + nb * 16 + lr], exp2f(s));
                }
        } else {
#pragma unroll
            for (int nb = 0; nb < 4; nb++)
#pragma unroll
                for (int r = 0; r < 4; r++)
                    stp(&Pt[(quad * 4 + r) * 72 + nb * 16 + lr], exp2f(sc[nb][r]));
        }
    };

    const int kbmax = qts[3];
    for (int kb = 0; kb <= kbmax; kb++) {
        const bool a0 = (kb <= qts[0]), a1 = (kb <= qts[1]), a2 = (kb <= qts[2]);
        f32x4 sa[4], sb[4];
        // ---- QK pair 1 (tiles 0,1) with current kf ----
        if (a0) qk_tile(0, sa);
        if (a1) qk_tile(1, sb);
        // ---- V loads for this kb (issued early; PV's vmcnt waits only these) ----
        s16x8 vf[8];
#pragma unroll
        for (int n = 0; n < 4; n++)
#pragma unroll
            for (int kc = 0; kc < 2; kc++)
                vf[n * 2 + kc] = *(const s16x8*)(vb + (size_t)(n * 16 + lr) * SEQ +
                                                 kb * 64 + kc * 32 + quad * 8);
        if (a0) store_tile(0, sa, kb);
        if (a1) store_tile(1, sb, kb);
        // ---- QK pair 2 (tiles 2,3) still with current kf ----
        if (a2) qk_tile(2, sa);
        qk_tile(3, sb);                       // tile 3 always active
        // ---- kf prefetch for kb+1 (kf now dead until next iteration) ----
        if (kb < kbmax) {
            const us* kp = kbase + (size_t)((kb + 1) * 64 + lr) * QKVN;
#pragma unroll
            for (int nb = 0; nb < 4; nb++) {
                kf[2 * nb]     = *(const s16x8*)(kp + (size_t)nb * 16 * QKVN + quad * 8);
                kf[2 * nb + 1] = *(const s16x8*)(kp + (size_t)nb * 16 * QKVN + 32 + quad * 8);
            }
        }
        if (a2) store_tile(2, sa, kb);
        store_tile(3, sb, kb);
        asm volatile("s_waitcnt lgkmcnt(0)" ::: "memory");   // wave-private tiles
        // ---- PV for all active tiles, shared vf ----
#pragma unroll
        for (int t = 0; t < 4; t++) {
            if (kb <= qts[t]) {
#pragma unroll
                for (int kc = 0; kc < 2; kc++) {
                    s16x8 pa = *(const s16x8*)&P[wave][t][lr * 72 + kc * 32 + quad * 8];
#pragma unroll
                    for (int n = 0; n < 4; n++)
                        oacc[t][n] = MFMA(pa, vf[n * 2 + kc], oacc[t][n]);
                    oacc[t][4] = MFMA(pa, onesb, oacc[t][4]);
                }
            }
        }
    }

#pragma unroll
    for (int t = 0; t < 4; t++)
#pragma unroll
        for (int r = 0; r < 4; r++) {
            float l = __shfl(oacc[t][4][r], lane & 48);
            float li = 1.0f / l;
#pragma unroll
            for (int n = 0; n < 4; n++)
                o[(size_t)(b * SEQ + q0[t] + quad * 4 + r) * DM + h * 64 + n * 16 + lr] =
                    f2bf(oacc[t][n][r] * li);
        }
}

// ---------------------------------------------------------------------------
extern "C" void kernel_launch(void* const* d_in, const int* in_sizes, int n_in,
                              void* d_out, int out_size, void* d_ws, size_t ws_size,
                              hipStream_t stream) {
    const float* x  = (const float*)d_in[0];
    const float* wq = (const float*)d_in[1];
    const float* wk = (const float*)d_in[2];
    const float* wv = (const float*)d_in[3];
    const float* wo = (const float*)d_in[4];
    float* out = (float*)d_out;

    char* ws = (char*)d_ws;
    const size_t MB = 1024 * 1024;
    us* xb     = (us*)(ws + 0 * MB);    // 16 MiB; reused as abuf (flash out)
    us* abuf   = (us*)(ws + 0 * MB);
    us* wqkvb  = (us*)(ws + 16 * MB);   // 12 MiB (wq|wk|wv) — contiguous with wob
    us* wob    = (us*)(ws + 28 * MB);   // 8 MiB
    us* qkvbuf = (us*)(ws + 36 * MB);   // 24 MiB (4096 x 3072)
    us* vtbuf  = (us*)(ws + 60 * MB);   // 4 MiB

    dim3 blk(256);
    cvt_f32_bf16<<<dim3(8192), blk, 0, stream>>>(x, xb, 2097152);
    cvt_weights<<<dim3(10240), blk, 0, stream>>>(wq, wk, wv, wo, wqkvb);

    gemm_bt<us, true><<<dim3(32, 24), blk, 0, stream>>>(xb, wqkvb, qkvbuf, 4096, 3072, 2048);
    transpose_v<<<dim3(32, 16), blk, 0, stream>>>(qkvbuf, vtbuf);
    flash_attn<<<dim3(8, 64), blk, 0, stream>>>(qkvbuf, vtbuf, abuf);
    gemm_bt<float, false><<<dim3(32, 16), blk, 0, stream>>>(abuf, wob, out, 4096, 2048, 2048);
}